// Round 2
// baseline (1283.249 us; speedup 1.0000x reference)
//
#include <hip/hip_runtime.h>
#include <hip/hip_bf16.h>
#include <stdint.h>

#define H_DIM  2048
#define IM_DIM 1024
#define E_NUM  16
#define TOPK   8
#define IS_DIM 2048
#define SCALE_F 2.5f

#define BM 128
#define BN 128
#define BK 32
#define LDSP 40   // fallback-path padded LDS row stride

typedef __attribute__((ext_vector_type(8))) short   short8;
typedef __attribute__((ext_vector_type(8))) __bf16  bf16x8;
typedef __attribute__((ext_vector_type(4))) float   float4v;
typedef unsigned short ushort_t;

// async global->LDS, 16B per lane; LDS dest = wave-uniform base + lane*16
#define GLOAD_LDS16(gp, lp) \
    __builtin_amdgcn_global_load_lds((__attribute__((address_space(1))) void*)(gp), \
                                     (__attribute__((address_space(3))) void*)(lp), 16, 0, 0)

static __device__ __forceinline__ ushort_t f2bf(float x) {
    union { float f; uint32_t u; } v; v.f = x;
    uint32_t r = v.u + 0x7fffu + ((v.u >> 16) & 1u);  // RNE
    return (ushort_t)(r >> 16);
}

// ---------------- zero helper ----------------
__global__ void zero4_kernel(float4* __restrict__ p, int n4) {
    int i = blockIdx.x * blockDim.x + threadIdx.x;
    if (i < n4) p[i] = make_float4(0.f, 0.f, 0.f, 0.f);
}

// ---------------- cast h (fp32 -> bf16) ----------------
__global__ void cast_h_kernel(const float* __restrict__ h, ushort_t* __restrict__ hb, int n4) {
    int i = blockIdx.x * blockDim.x + threadIdx.x;
    if (i < n4) {
        float4 v = ((const float4*)h)[i];
        ushort4 o;
        o.x = f2bf(v.x); o.y = f2bf(v.y); o.z = f2bf(v.z); o.w = f2bf(v.w);
        ((ushort4*)hb)[i] = o;
    }
}

// ------- router: sigmoid + top-8 -> dense comb[T,E] AND per-expert gather lists -------
__global__ void router_kernel(const float* __restrict__ h, const float* __restrict__ gw,
                              float* __restrict__ comb,
                              int* __restrict__ cnt, int* __restrict__ tlist,
                              float* __restrict__ wlist, int T) {
    int t = blockIdx.x;
    int l = threadIdx.x;
    const float* hr = h + (size_t)t * H_DIM;
    __shared__ float logits[E_NUM];
    for (int e = 0; e < E_NUM; e++) {
        const float* g = gw + e * H_DIM;
        float p = 0.f;
        #pragma unroll 8
        for (int j = l; j < H_DIM; j += 64) p += hr[j] * g[j];
        #pragma unroll
        for (int off = 32; off > 0; off >>= 1) p += __shfl_down(p, off);
        if (l == 0) logits[e] = p;
    }
    __syncthreads();
    if (l == 0) {
        float sig[E_NUM]; bool sel[E_NUM];
        #pragma unroll
        for (int e = 0; e < E_NUM; e++) { sig[e] = 1.f / (1.f + expf(-logits[e])); sel[e] = false; }
        #pragma unroll
        for (int k = 0; k < TOPK; k++) {
            int bi = 0; float bv = -1.f;
            #pragma unroll
            for (int e = 0; e < E_NUM; e++)
                if (!sel[e] && sig[e] > bv) { bv = sig[e]; bi = e; }
            sel[bi] = true;
        }
        float s = 0.f;
        #pragma unroll
        for (int e = 0; e < E_NUM; e++) if (sel[e]) s += sig[e];
        float inv = SCALE_F / (s + 1e-6f);
        #pragma unroll
        for (int e = 0; e < E_NUM; e++) {
            float w = sel[e] ? sig[e] * inv : 0.f;
            comb[(size_t)t * E_NUM + e] = w;
            if (sel[e]) {
                int pos = atomicAdd(&cnt[e], 1);
                tlist[(size_t)e * T + pos] = t;
                wlist[(size_t)e * T + pos] = w;
            }
        }
    }
}

// ---------------- transpose+convert: fp32 [z][K][N-slab] -> bf16 [z][N][K] ----------------
__global__ __launch_bounds__(256)
void transpose_cvt_kernel(const float* __restrict__ src, ushort_t* __restrict__ dst,
                          int K, int N, size_t sStride, size_t dStride)
{
    __shared__ float tile[64 * 65];
    int z = blockIdx.z;
    const float* S = src + (size_t)z * sStride;
    ushort_t* D = dst + (size_t)z * dStride;
    int k0 = blockIdx.x * 64, n0 = blockIdx.y * 64;
    int tid = threadIdx.x;
    int tr = tid >> 4, tc = (tid & 15) * 4;
    #pragma unroll
    for (int p = 0; p < 4; p++) {
        int r = tr + 16 * p;
        float4 v = *(const float4*)&S[(size_t)(k0 + r) * N + n0 + tc];
        tile[(tc + 0) * 65 + r] = v.x;
        tile[(tc + 1) * 65 + r] = v.y;
        tile[(tc + 2) * 65 + r] = v.z;
        tile[(tc + 3) * 65 + r] = v.w;
    }
    __syncthreads();
    #pragma unroll
    for (int p = 0; p < 4; p++) {
        int n = tr + 16 * p;
        ushort4 o;
        o.x = f2bf(tile[n * 65 + tc + 0]);
        o.y = f2bf(tile[n * 65 + tc + 1]);
        o.z = f2bf(tile[n * 65 + tc + 2]);
        o.w = f2bf(tile[n * 65 + tc + 3]);
        *(ushort4*)&D[(size_t)(n0 + n) * K + k0 + tc] = o;
    }
}

// ================= FAST PATH: m97-style GEMMs, B pre-transposed bf16 [N,K] ============

// GEMM1 (dense, shared expert): C = silu(A@Bg^T) * (A@Bu^T), bf16 out
__global__ __launch_bounds__(256, 2)
void gemm1f_kernel(const ushort_t* __restrict__ A, int lda,
                   const ushort_t* __restrict__ Bg0, const ushort_t* __restrict__ Bu0,
                   size_t bSeg,
                   ushort_t* __restrict__ C0, size_t cSeg, int ldc,
                   const float* __restrict__ comb, int Kdim)
{
    __shared__ ushort_t Als[BM * BK];
    __shared__ ushort_t Bgs[BN * BK];
    __shared__ ushort_t Bus[BN * BK];

    int z = blockIdx.z;
    const ushort_t* Bg = Bg0 + (size_t)z * bSeg;
    const ushort_t* Bu = Bu0 + (size_t)z * bSeg;
    ushort_t* C = C0 + (size_t)z * cSeg;
    int t0 = blockIdx.x * BM, n0 = blockIdx.y * BN;
    int tid = threadIdx.x, lane = tid & 63, wid = tid >> 6;
    int wm = (wid & 1) * 64, wn = (wid >> 1) * 64;
    int quad = lane >> 4, l15 = lane & 15;

    int srow = lane >> 2;          // 0..15
    int scol = (lane & 3) * 8;     // element col (16B granules)
    int rb = wid * 32;             // wave's 32-row slab

    float4v accg[4][4], accu[4][4];
    #pragma unroll
    for (int i = 0; i < 4; i++)
        #pragma unroll
        for (int j = 0; j < 4; j++) {
            accg[i][j] = (float4v){0.f, 0.f, 0.f, 0.f};
            accu[i][j] = (float4v){0.f, 0.f, 0.f, 0.f};
        }

    const ushort_t* Ab0  = A  + (size_t)(t0 + rb + srow)      * lda  + scol;
    const ushort_t* Ab1  = A  + (size_t)(t0 + rb + 16 + srow) * lda  + scol;
    const ushort_t* Bgb0 = Bg + (size_t)(n0 + rb + srow)      * Kdim + scol;
    const ushort_t* Bgb1 = Bg + (size_t)(n0 + rb + 16 + srow) * Kdim + scol;
    const ushort_t* Bub0 = Bu + (size_t)(n0 + rb + srow)      * Kdim + scol;
    const ushort_t* Bub1 = Bu + (size_t)(n0 + rb + 16 + srow) * Kdim + scol;
    ushort_t* lA0  = &Als[rb * BK];
    ushort_t* lA1  = &Als[(rb + 16) * BK];
    ushort_t* lBg0 = &Bgs[rb * BK];
    ushort_t* lBg1 = &Bgs[(rb + 16) * BK];
    ushort_t* lBu0 = &Bus[rb * BK];
    ushort_t* lBu1 = &Bus[(rb + 16) * BK];

    for (int k0 = 0; k0 < Kdim; k0 += BK) {
        GLOAD_LDS16(Ab0 + k0,  lA0);
        GLOAD_LDS16(Ab1 + k0,  lA1);
        GLOAD_LDS16(Bgb0 + k0, lBg0);
        GLOAD_LDS16(Bgb1 + k0, lBg1);
        GLOAD_LDS16(Bub0 + k0, lBu0);
        GLOAD_LDS16(Bub1 + k0, lBu1);
        __syncthreads();

        bf16x8 af[4], bg[4], bu[4];
        #pragma unroll
        for (int i = 0; i < 4; i++)
            af[i] = *(const bf16x8*)&Als[(wm + i * 16 + l15) * BK + quad * 8];
        #pragma unroll
        for (int j = 0; j < 4; j++) {
            bg[j] = *(const bf16x8*)&Bgs[(wn + j * 16 + l15) * BK + quad * 8];
            bu[j] = *(const bf16x8*)&Bus[(wn + j * 16 + l15) * BK + quad * 8];
        }
        #pragma unroll
        for (int i = 0; i < 4; i++)
            #pragma unroll
            for (int j = 0; j < 4; j++) {
                accg[i][j] = __builtin_amdgcn_mfma_f32_16x16x32_bf16(af[i], bg[j], accg[i][j], 0, 0, 0);
                accu[i][j] = __builtin_amdgcn_mfma_f32_16x16x32_bf16(af[i], bu[j], accu[i][j], 0, 0, 0);
            }
        __syncthreads();
    }

    #pragma unroll
    for (int i = 0; i < 4; i++) {
        #pragma unroll
        for (int r = 0; r < 4; r++) {
            int t = t0 + wm + i * 16 + quad * 4 + r;
            float sc = comb ? comb[(size_t)t * E_NUM + z] : 1.f;
            #pragma unroll
            for (int j = 0; j < 4; j++) {
                float g = accg[i][j][r], u = accu[i][j][r];
                float sg = g / (1.f + __expf(-g));
                float v = sg * u * sc;
                int c = n0 + wn + j * 16 + l15;
                C[(size_t)t * ldc + c] = f2bf(v);
            }
        }
    }
}

// GEMM1 gathered (routed experts): A rows gathered via tlist; epilogue scales by wlist.
__global__ __launch_bounds__(256, 2)
void gemm1g_kernel(const ushort_t* __restrict__ A,      // h_bf [T][H]
                   const ushort_t* __restrict__ Bg0,    // [E][IM][H]
                   const ushort_t* __restrict__ Bu0,    // [E][IM][H]
                   ushort_t* __restrict__ C0,           // [E][T][IM] (compact per expert)
                   const int* __restrict__ cnt,
                   const int* __restrict__ tlist,
                   const float* __restrict__ wlist, int T)
{
    __shared__ ushort_t Als[BM * BK];
    __shared__ ushort_t Bgs[BN * BK];
    __shared__ ushort_t Bus[BN * BK];

    int z = blockIdx.z;
    int cn = cnt[z];
    int t0 = blockIdx.x * BM;
    if (t0 >= cn) return;                 // empty tile: whole block exits together

    const ushort_t* Bg = Bg0 + (size_t)z * IM_DIM * H_DIM;
    const ushort_t* Bu = Bu0 + (size_t)z * IM_DIM * H_DIM;
    ushort_t* C = C0 + (size_t)z * T * IM_DIM;
    const int* tl = tlist + (size_t)z * T;
    int n0 = blockIdx.y * BN;
    int tid = threadIdx.x, lane = tid & 63, wid = tid >> 6;
    int wm = (wid & 1) * 64, wn = (wid >> 1) * 64;
    int quad = lane >> 4, l15 = lane & 15;

    int srow = lane >> 2;
    int scol = (lane & 3) * 8;
    int rb = wid * 32;

    float4v accg[4][4], accu[4][4];
    #pragma unroll
    for (int i = 0; i < 4; i++)
        #pragma unroll
        for (int j = 0; j < 4; j++) {
            accg[i][j] = (float4v){0.f, 0.f, 0.f, 0.f};
            accu[i][j] = (float4v){0.f, 0.f, 0.f, 0.f};
        }

    // gather: per-lane global source rows (pad positions clamp to last valid row;
    // their outputs are computed but never stored — MFMA rows are independent)
    int p0 = t0 + rb + srow, p1 = p0 + 16;
    int r0 = tl[p0 < cn ? p0 : cn - 1];
    int r1 = tl[p1 < cn ? p1 : cn - 1];
    const ushort_t* Ab0  = A  + (size_t)r0 * H_DIM + scol;
    const ushort_t* Ab1  = A  + (size_t)r1 * H_DIM + scol;
    const ushort_t* Bgb0 = Bg + (size_t)(n0 + rb + srow)      * H_DIM + scol;
    const ushort_t* Bgb1 = Bg + (size_t)(n0 + rb + 16 + srow) * H_DIM + scol;
    const ushort_t* Bub0 = Bu + (size_t)(n0 + rb + srow)      * H_DIM + scol;
    const ushort_t* Bub1 = Bu + (size_t)(n0 + rb + 16 + srow) * H_DIM + scol;
    ushort_t* lA0  = &Als[rb * BK];
    ushort_t* lA1  = &Als[(rb + 16) * BK];
    ushort_t* lBg0 = &Bgs[rb * BK];
    ushort_t* lBg1 = &Bgs[(rb + 16) * BK];
    ushort_t* lBu0 = &Bus[rb * BK];
    ushort_t* lBu1 = &Bus[(rb + 16) * BK];

    for (int k0 = 0; k0 < H_DIM; k0 += BK) {
        GLOAD_LDS16(Ab0 + k0,  lA0);
        GLOAD_LDS16(Ab1 + k0,  lA1);
        GLOAD_LDS16(Bgb0 + k0, lBg0);
        GLOAD_LDS16(Bgb1 + k0, lBg1);
        GLOAD_LDS16(Bub0 + k0, lBu0);
        GLOAD_LDS16(Bub1 + k0, lBu1);
        __syncthreads();

        bf16x8 af[4], bg[4], bu[4];
        #pragma unroll
        for (int i = 0; i < 4; i++)
            af[i] = *(const bf16x8*)&Als[(wm + i * 16 + l15) * BK + quad * 8];
        #pragma unroll
        for (int j = 0; j < 4; j++) {
            bg[j] = *(const bf16x8*)&Bgs[(wn + j * 16 + l15) * BK + quad * 8];
            bu[j] = *(const bf16x8*)&Bus[(wn + j * 16 + l15) * BK + quad * 8];
        }
        #pragma unroll
        for (int i = 0; i < 4; i++)
            #pragma unroll
            for (int j = 0; j < 4; j++) {
                accg[i][j] = __builtin_amdgcn_mfma_f32_16x16x32_bf16(af[i], bg[j], accg[i][j], 0, 0, 0);
                accu[i][j] = __builtin_amdgcn_mfma_f32_16x16x32_bf16(af[i], bu[j], accu[i][j], 0, 0, 0);
            }
        __syncthreads();
    }

    #pragma unroll
    for (int i = 0; i < 4; i++) {
        #pragma unroll
        for (int r = 0; r < 4; r++) {
            int pos = t0 + wm + i * 16 + quad * 4 + r;
            if (pos < cn) {
                float sc = wlist[(size_t)z * T + pos];
                #pragma unroll
                for (int j = 0; j < 4; j++) {
                    float g = accg[i][j][r], u = accu[i][j][r];
                    float sg = g / (1.f + __expf(-g));
                    float v = sg * u * sc;
                    int c = n0 + wn + j * 16 + l15;
                    C[(size_t)pos * IM_DIM + c] = f2bf(v);
                }
            }
        }
    }
}

// GEMM2 (dense, shared expert): Out (=|+=) sum_seg A_seg @ B_seg^T, fp32 out
__global__ __launch_bounds__(256, 2)
void gemm2f_kernel(const ushort_t* __restrict__ A0, size_t aSeg, int lda,
                   const ushort_t* __restrict__ B0, size_t bSeg,
                   float* __restrict__ Out, int N,
                   int nsegPerZ, int Kper, int mode)
{
    __shared__ ushort_t Als[BM * BK];
    __shared__ ushort_t Bls[BN * BK];

    int t0 = blockIdx.x * BM, n0 = blockIdx.y * BN;
    int z = blockIdx.z;
    int tid = threadIdx.x, lane = tid & 63, wid = tid >> 6;
    int wm = (wid & 1) * 64, wn = (wid >> 1) * 64;
    int quad = lane >> 4, l15 = lane & 15;

    int srow = lane >> 2;
    int scol = (lane & 3) * 8;
    int rb = wid * 32;

    float4v acc[4][4];
    #pragma unroll
    for (int i = 0; i < 4; i++)
        #pragma unroll
        for (int j = 0; j < 4; j++) acc[i][j] = (float4v){0.f, 0.f, 0.f, 0.f};

    ushort_t* lA0 = &Als[rb * BK];
    ushort_t* lA1 = &Als[(rb + 16) * BK];
    ushort_t* lB0 = &Bls[rb * BK];
    ushort_t* lB1 = &Bls[(rb + 16) * BK];

    for (int s = 0; s < nsegPerZ; s++) {
        int seg = z * nsegPerZ + s;
        const ushort_t* A = A0 + (size_t)seg * aSeg;
        const ushort_t* B = B0 + (size_t)seg * bSeg;
        const ushort_t* Ab0 = A + (size_t)(t0 + rb + srow)      * lda  + scol;
        const ushort_t* Ab1 = A + (size_t)(t0 + rb + 16 + srow) * lda  + scol;
        const ushort_t* Bb0 = B + (size_t)(n0 + rb + srow)      * Kper + scol;
        const ushort_t* Bb1 = B + (size_t)(n0 + rb + 16 + srow) * Kper + scol;

        for (int k0 = 0; k0 < Kper; k0 += BK) {
            GLOAD_LDS16(Ab0 + k0, lA0);
            GLOAD_LDS16(Ab1 + k0, lA1);
            GLOAD_LDS16(Bb0 + k0, lB0);
            GLOAD_LDS16(Bb1 + k0, lB1);
            __syncthreads();

            bf16x8 af[4], bf[4];
            #pragma unroll
            for (int i = 0; i < 4; i++)
                af[i] = *(const bf16x8*)&Als[(wm + i * 16 + l15) * BK + quad * 8];
            #pragma unroll
            for (int j = 0; j < 4; j++)
                bf[j] = *(const bf16x8*)&Bls[(wn + j * 16 + l15) * BK + quad * 8];
            #pragma unroll
            for (int i = 0; i < 4; i++)
                #pragma unroll
                for (int j = 0; j < 4; j++)
                    acc[i][j] = __builtin_amdgcn_mfma_f32_16x16x32_bf16(af[i], bf[j], acc[i][j], 0, 0, 0);
            __syncthreads();
        }
    }

    #pragma unroll
    for (int i = 0; i < 4; i++) {
        #pragma unroll
        for (int r = 0; r < 4; r++) {
            int t = t0 + wm + i * 16 + quad * 4 + r;
            #pragma unroll
            for (int j = 0; j < 4; j++) {
                int c = n0 + wn + j * 16 + l15;
                size_t idx = (size_t)t * N + c;
                float v = acc[i][j][r];
                if (mode == 0) Out[idx] = v;
                else if (mode == 1) Out[idx] += v;
                else atomicAdd(&Out[idx], v);
            }
        }
    }
}

// GEMM2 gathered (routed experts): per-expert compact A, scatter-atomicAdd to Out rows.
__global__ __launch_bounds__(256, 2)
void gemm2g_kernel(const ushort_t* __restrict__ A0,   // [E][T][IM] compact
                   const ushort_t* __restrict__ B0,   // [E][H][IM]
                   float* __restrict__ Out,
                   const int* __restrict__ cnt,
                   const int* __restrict__ tlist, int T)
{
    __shared__ ushort_t Als[BM * BK];
    __shared__ ushort_t Bls[BN * BK];

    int z = blockIdx.z;
    int cn = cnt[z];
    int t0 = blockIdx.x * BM;
    if (t0 >= cn) return;

    const ushort_t* A = A0 + (size_t)z * T * IM_DIM;
    const ushort_t* B = B0 + (size_t)z * H_DIM * IM_DIM;
    const int* tl = tlist + (size_t)z * T;
    int n0 = blockIdx.y * BN;
    int tid = threadIdx.x, lane = tid & 63, wid = tid >> 6;
    int wm = (wid & 1) * 64, wn = (wid >> 1) * 64;
    int quad = lane >> 4, l15 = lane & 15;

    int srow = lane >> 2;
    int scol = (lane & 3) * 8;
    int rb = wid * 32;

    float4v acc[4][4];
    #pragma unroll
    for (int i = 0; i < 4; i++)
        #pragma unroll
        for (int j = 0; j < 4; j++) acc[i][j] = (float4v){0.f, 0.f, 0.f, 0.f};

    const ushort_t* Ab0 = A + (size_t)(t0 + rb + srow)      * IM_DIM + scol;
    const ushort_t* Ab1 = A + (size_t)(t0 + rb + 16 + srow) * IM_DIM + scol;
    const ushort_t* Bb0 = B + (size_t)(n0 + rb + srow)      * IM_DIM + scol;
    const ushort_t* Bb1 = B + (size_t)(n0 + rb + 16 + srow) * IM_DIM + scol;
    ushort_t* lA0 = &Als[rb * BK];
    ushort_t* lA1 = &Als[(rb + 16) * BK];
    ushort_t* lB0 = &Bls[rb * BK];
    ushort_t* lB1 = &Bls[(rb + 16) * BK];

    for (int k0 = 0; k0 < IM_DIM; k0 += BK) {
        GLOAD_LDS16(Ab0 + k0, lA0);
        GLOAD_LDS16(Ab1 + k0, lA1);
        GLOAD_LDS16(Bb0 + k0, lB0);
        GLOAD_LDS16(Bb1 + k0, lB1);
        __syncthreads();

        bf16x8 af[4], bf[4];
        #pragma unroll
        for (int i = 0; i < 4; i++)
            af[i] = *(const bf16x8*)&Als[(wm + i * 16 + l15) * BK + quad * 8];
        #pragma unroll
        for (int j = 0; j < 4; j++)
            bf[j] = *(const bf16x8*)&Bls[(wn + j * 16 + l15) * BK + quad * 8];
        #pragma unroll
        for (int i = 0; i < 4; i++)
            #pragma unroll
            for (int j = 0; j < 4; j++)
                acc[i][j] = __builtin_amdgcn_mfma_f32_16x16x32_bf16(af[i], bf[j], acc[i][j], 0, 0, 0);
        __syncthreads();
    }

    #pragma unroll
    for (int i = 0; i < 4; i++) {
        #pragma unroll
        for (int r = 0; r < 4; r++) {
            int pos = t0 + wm + i * 16 + quad * 4 + r;
            if (pos < cn) {
                int tok = tl[pos];
                #pragma unroll
                for (int j = 0; j < 4; j++) {
                    int c = n0 + wn + j * 16 + l15;
                    atomicAdd(&Out[(size_t)tok * H_DIM + c], acc[i][j][r]);
                }
            }
        }
    }
}

// ================= FALLBACK PATH (round-1 kernels, ws-lean) ==========================

__global__ __launch_bounds__(256)
void gemm1_kernel(const ushort_t* __restrict__ A, int lda,
                  const float* __restrict__ Bg0, const float* __restrict__ Bu0,
                  size_t bSeg, int ldb,
                  ushort_t* __restrict__ C0, size_t cSeg, int ldc,
                  const float* __restrict__ comb, int Kdim)
{
    __shared__ ushort_t Als[BM * LDSP];
    __shared__ ushort_t Bgs[BN * LDSP];
    __shared__ ushort_t Bus[BN * LDSP];

    int z = blockIdx.z;
    const float* Bg = Bg0 + (size_t)z * bSeg;
    const float* Bu = Bu0 + (size_t)z * bSeg;
    ushort_t* C = C0 + (size_t)z * cSeg;

    int t0 = blockIdx.x * BM;
    int n0 = blockIdx.y * BN;
    int tid = threadIdx.x;
    int lane = tid & 63, wid = tid >> 6;
    int wm = (wid & 1) * 64, wn = (wid >> 1) * 64;
    int quad = lane >> 4, l15 = lane & 15;

    float4v accg[4][4], accu[4][4];
    #pragma unroll
    for (int i = 0; i < 4; i++)
        #pragma unroll
        for (int j = 0; j < 4; j++) {
            accg[i][j] = (float4v){0.f, 0.f, 0.f, 0.f};
            accu[i][j] = (float4v){0.f, 0.f, 0.f, 0.f};
        }

    int a_r  = tid >> 2, a_oc = tid & 3;
    int b_ko = (tid >> 4) & 3;
    int b_n  = 2 * ((tid & 15) + ((tid >> 6) << 4));

    for (int k0 = 0; k0 < Kdim; k0 += BK) {
        __syncthreads();
        {
            const ushort_t* s0 = A + (size_t)(t0 + a_r) * lda + k0 + a_oc * 8;
            *(short8*)&Als[a_r * LDSP + a_oc * 8] = *(const short8*)s0;
            const ushort_t* s1 = A + (size_t)(t0 + a_r + 64) * lda + k0 + a_oc * 8;
            *(short8*)&Als[(a_r + 64) * LDSP + a_oc * 8] = *(const short8*)s1;
        }
        {
            short8 g0, g1, u0, u1;
            #pragma unroll
            for (int j = 0; j < 8; j++) {
                size_t roff = (size_t)(k0 + b_ko * 8 + j) * ldb + n0 + b_n;
                float2 vg = *(const float2*)&Bg[roff];
                float2 vu = *(const float2*)&Bu[roff];
                g0[j] = (short)f2bf(vg.x); g1[j] = (short)f2bf(vg.y);
                u0[j] = (short)f2bf(vu.x); u1[j] = (short)f2bf(vu.y);
            }
            *(short8*)&Bgs[b_n * LDSP + b_ko * 8]       = g0;
            *(short8*)&Bgs[(b_n + 1) * LDSP + b_ko * 8] = g1;
            *(short8*)&Bus[b_n * LDSP + b_ko * 8]       = u0;
            *(short8*)&Bus[(b_n + 1) * LDSP + b_ko * 8] = u1;
        }
        __syncthreads();

        bf16x8 af[4], bg[4], bu[4];
        #pragma unroll
        for (int i = 0; i < 4; i++)
            af[i] = *(const bf16x8*)&Als[(wm + i * 16 + l15) * LDSP + quad * 8];
        #pragma unroll
        for (int j = 0; j < 4; j++) {
            bg[j] = *(const bf16x8*)&Bgs[(wn + j * 16 + l15) * LDSP + quad * 8];
            bu[j] = *(const bf16x8*)&Bus[(wn + j * 16 + l15) * LDSP + quad * 8];
        }
        #pragma unroll
        for (int i = 0; i < 4; i++)
            #pragma unroll
            for (int j = 0; j < 4; j++) {
                accg[i][j] = __builtin_amdgcn_mfma_f32_16x16x32_bf16(af[i], bg[j], accg[i][j], 0, 0, 0);
                accu[i][j] = __builtin_amdgcn_mfma_f32_16x16x32_bf16(af[i], bu[j], accu[i][j], 0, 0, 0);
            }
    }

    #pragma unroll
    for (int i = 0; i < 4; i++) {
        #pragma unroll
        for (int r = 0; r < 4; r++) {
            int t = t0 + wm + i * 16 + quad * 4 + r;
            float sc = comb ? comb[(size_t)t * E_NUM + z] : 1.f;
            #pragma unroll
            for (int j = 0; j < 4; j++) {
                float g = accg[i][j][r], u = accu[i][j][r];
                float sg = g / (1.f + __expf(-g));
                float v = sg * u * sc;
                int c = n0 + wn + j * 16 + l15;
                C[(size_t)t * ldc + c] = f2bf(v);
            }
        }
    }
}

__global__ __launch_bounds__(256)
void gemm2_kernel(const ushort_t* __restrict__ A0, size_t aSeg, int lda,
                  const float* __restrict__ B0, size_t bSeg, int ldb,
                  float* __restrict__ Out, int N,
                  int nseg, int Kper, int accum)
{
    __shared__ ushort_t Als[BM * LDSP];
    __shared__ ushort_t Bls[BN * LDSP];

    int t0 = blockIdx.x * BM;
    int n0 = blockIdx.y * BN;
    int tid = threadIdx.x;
    int lane = tid & 63, wid = tid >> 6;
    int wm = (wid & 1) * 64, wn = (wid >> 1) * 64;
    int quad = lane >> 4, l15 = lane & 15;

    float4v acc[4][4];
    #pragma unroll
    for (int i = 0; i < 4; i++)
        #pragma unroll
        for (int j = 0; j < 4; j++) acc[i][j] = (float4v){0.f, 0.f, 0.f, 0.f};

    int a_r  = tid >> 2, a_oc = tid & 3;
    int b_ko = (tid >> 4) & 3;
    int b_n  = 2 * ((tid & 15) + ((tid >> 6) << 4));

    for (int seg = 0; seg < nseg; seg++) {
        const ushort_t* A = A0 + (size_t)seg * aSeg;
        const float*    B = B0 + (size_t)seg * bSeg;
        for (int k0 = 0; k0 < Kper; k0 += BK) {
            __syncthreads();
            {
                const ushort_t* s0 = A + (size_t)(t0 + a_r) * lda + k0 + a_oc * 8;
                *(short8*)&Als[a_r * LDSP + a_oc * 8] = *(const short8*)s0;
                const ushort_t* s1 = A + (size_t)(t0 + a_r + 64) * lda + k0 + a_oc * 8;
                *(short8*)&Als[(a_r + 64) * LDSP + a_oc * 8] = *(const short8*)s1;
            }
            {
                short8 r0, r1;
                #pragma unroll
                for (int j = 0; j < 8; j++) {
                    size_t roff = (size_t)(k0 + b_ko * 8 + j) * ldb + n0 + b_n;
                    float2 v = *(const float2*)&B[roff];
                    r0[j] = (short)f2bf(v.x); r1[j] = (short)f2bf(v.y);
                }
                *(short8*)&Bls[b_n * LDSP + b_ko * 8]       = r0;
                *(short8*)&Bls[(b_n + 1) * LDSP + b_ko * 8] = r1;
            }
            __syncthreads();

            bf16x8 af[4], bf[4];
            #pragma unroll
            for (int i = 0; i < 4; i++)
                af[i] = *(const bf16x8*)&Als[(wm + i * 16 + l15) * LDSP + quad * 8];
            #pragma unroll
            for (int j = 0; j < 4; j++)
                bf[j] = *(const bf16x8*)&Bls[(wn + j * 16 + l15) * LDSP + quad * 8];
            #pragma unroll
            for (int i = 0; i < 4; i++)
                #pragma unroll
                for (int j = 0; j < 4; j++)
                    acc[i][j] = __builtin_amdgcn_mfma_f32_16x16x32_bf16(af[i], bf[j], acc[i][j], 0, 0, 0);
        }
    }

    #pragma unroll
    for (int i = 0; i < 4; i++) {
        #pragma unroll
        for (int r = 0; r < 4; r++) {
            int t = t0 + wm + i * 16 + quad * 4 + r;
            #pragma unroll
            for (int j = 0; j < 4; j++) {
                int c = n0 + wn + j * 16 + l15;
                size_t idx = (size_t)t * N + c;
                float v = acc[i][j][r];
                if (accum) Out[idx] += v; else Out[idx] = v;
            }
        }
    }
}

// =====================================================================================

extern "C" void kernel_launch(void* const* d_in, const int* in_sizes, int n_in,
                              void* d_out, int out_size, void* d_ws, size_t ws_size,
                              hipStream_t stream) {
    const float* h      = (const float*)d_in[0];
    const float* gate_w = (const float*)d_in[1];
    const float* Wg     = (const float*)d_in[2];
    const float* Wu     = (const float*)d_in[3];
    const float* Wd     = (const float*)d_in[4];
    const float* sWg    = (const float*)d_in[5];
    const float* sWu    = (const float*)d_in[6];
    const float* sWd    = (const float*)d_in[7];
    float* out = (float*)d_out;
    int T = in_sizes[0] / H_DIM;
    (void)n_in; (void)out_size;

    char* ws = (char*)d_ws;
    size_t off = 0;
    auto alloc = [&](size_t bytes) -> void* {
        void* p = ws + off;
        off = (off + bytes + 255) & ~(size_t)255;
        return p;
    };
    ushort_t* h_bf  = (ushort_t*)alloc((size_t)T * H_DIM * 2);
    float*    comb  = (float*)   alloc((size_t)T * E_NUM * 4);
    int*      cnt   = (int*)     alloc((size_t)E_NUM * 4);
    int*      tlist = (int*)     alloc((size_t)E_NUM * T * 4);
    float*    wlist = (float*)   alloc((size_t)E_NUM * T * 4);
    ushort_t* act_s = (ushort_t*)alloc((size_t)T * IS_DIM * 2);
    ushort_t* act_r = (ushort_t*)alloc((size_t)E_NUM * T * IM_DIM * 2);
    // fast-path weight buffers (reused over launch sequence)
    ushort_t* bufS1 = (ushort_t*)alloc((size_t)IS_DIM * H_DIM * 2);          // 8 MB
    ushort_t* bufS2 = (ushort_t*)alloc((size_t)IS_DIM * H_DIM * 2);          // 8 MB
    ushort_t* bufW1 = (ushort_t*)alloc((size_t)E_NUM * IM_DIM * H_DIM * 2);  // 64 MB
    ushort_t* bufW2 = (ushort_t*)alloc((size_t)E_NUM * IM_DIM * H_DIM * 2);  // 64 MB
    size_t need = off;

    int n4 = T * H_DIM / 4;
    cast_h_kernel<<<(n4 + 255) / 256, 256, 0, stream>>>(h, h_bf, n4);
    zero4_kernel<<<1, 64, 0, stream>>>((float4*)cnt, E_NUM * 4 / 16);
    router_kernel<<<T, 64, 0, stream>>>(h, gate_w, comb, cnt, tlist, wlist, T);

    if (ws_size >= need) {
        // ---- fast path: pre-transposed bf16 weights + gathered routed GEMMs ----
        // shared gate/up weights: [H][IS] -> [IS][H]
        transpose_cvt_kernel<<<dim3(H_DIM / 64, IS_DIM / 64, 1), 256, 0, stream>>>(
            sWg, bufS1, H_DIM, IS_DIM, 0, 0);
        transpose_cvt_kernel<<<dim3(H_DIM / 64, IS_DIM / 64, 1), 256, 0, stream>>>(
            sWu, bufS2, H_DIM, IS_DIM, 0, 0);
        gemm1f_kernel<<<dim3(T / BM, IS_DIM / BN, 1), 256, 0, stream>>>(
            h_bf, H_DIM, bufS1, bufS2, 0, act_s, 0, IS_DIM, nullptr, H_DIM);

        // routed gate/up weights: [E][H][IM] -> [E][IM][H]
        transpose_cvt_kernel<<<dim3(H_DIM / 64, IM_DIM / 64, E_NUM), 256, 0, stream>>>(
            Wg, bufW1, H_DIM, IM_DIM, (size_t)H_DIM * IM_DIM, (size_t)IM_DIM * H_DIM);
        transpose_cvt_kernel<<<dim3(H_DIM / 64, IM_DIM / 64, E_NUM), 256, 0, stream>>>(
            Wu, bufW2, H_DIM, IM_DIM, (size_t)H_DIM * IM_DIM, (size_t)IM_DIM * H_DIM);
        gemm1g_kernel<<<dim3(T / BM, IM_DIM / BN, E_NUM), 256, 0, stream>>>(
            h_bf, bufW1, bufW2, act_r, cnt, tlist, wlist, T);

        // shared down weight: [IS][H] -> [H][IS]; writes out (mode 0)
        transpose_cvt_kernel<<<dim3(IS_DIM / 64, H_DIM / 64, 1), 256, 0, stream>>>(
            sWd, bufS1, IS_DIM, H_DIM, 0, 0);
        gemm2f_kernel<<<dim3(T / BM, H_DIM / BN, 1), 256, 0, stream>>>(
            act_s, 0, IS_DIM, bufS1, 0, out, H_DIM, 1, IS_DIM, 0);

        // routed down weight: [E][IM][H] -> [E][H][IM]; scatter-atomicAdd on top
        transpose_cvt_kernel<<<dim3(IM_DIM / 64, H_DIM / 64, E_NUM), 256, 0, stream>>>(
            Wd, bufW1, IM_DIM, H_DIM, (size_t)IM_DIM * H_DIM, (size_t)H_DIM * IM_DIM);
        gemm2g_kernel<<<dim3(T / BM, H_DIM / BN, E_NUM), 256, 0, stream>>>(
            act_r, bufW1, out, cnt, tlist, T);
    } else {
        // ---- fallback: round-1 path (~80 MB ws) ----
        gemm1_kernel<<<dim3(T / BM, IS_DIM / BN, 1), 256, 0, stream>>>(
            h_bf, H_DIM, sWg, sWu, 0, IS_DIM, act_s, 0, IS_DIM, nullptr, H_DIM);
        gemm1_kernel<<<dim3(T / BM, IM_DIM / BN, E_NUM), 256, 0, stream>>>(
            h_bf, H_DIM, Wg, Wu, (size_t)H_DIM * IM_DIM, IM_DIM,
            act_r, (size_t)T * IM_DIM, IM_DIM, comb, H_DIM);
        gemm2_kernel<<<dim3(T / BM, H_DIM / BN, 1), 256, 0, stream>>>(
            act_s, 0, IS_DIM, sWd, 0, H_DIM, out, H_DIM, 1, IS_DIM, 0);
        gemm2_kernel<<<dim3(T / BM, H_DIM / BN, 1), 256, 0, stream>>>(
            act_r, (size_t)T * IM_DIM, IM_DIM, Wd, (size_t)IM_DIM * H_DIM, H_DIM,
            out, H_DIM, E_NUM, IM_DIM, 1);
    }
}

// Round 3
// 1154.397 us; speedup vs baseline: 1.1116x; 1.1116x over previous
//
#include <hip/hip_runtime.h>
#include <hip/hip_bf16.h>
#include <stdint.h>

#define H_DIM  2048
#define IM_DIM 1024
#define E_NUM  16
#define TOPK   8
#define IS_DIM 2048
#define SCALE_F 2.5f

#define BM 128
#define BN 128
#define BK 32
#define LDSP 40   // fallback-path padded LDS row stride

typedef __attribute__((ext_vector_type(8))) short   short8;
typedef __attribute__((ext_vector_type(8))) __bf16  bf16x8;
typedef __attribute__((ext_vector_type(4))) float   float4v;
typedef unsigned short ushort_t;

// async global->LDS, 16B per lane; LDS dest = wave-uniform base + lane*16
#define GLOAD_LDS16(gp, lp) \
    __builtin_amdgcn_global_load_lds((__attribute__((address_space(1))) void*)(gp), \
                                     (__attribute__((address_space(3))) void*)(lp), 16, 0, 0)

static __device__ __forceinline__ ushort_t f2bf(float x) {
    union { float f; uint32_t u; } v; v.f = x;
    uint32_t r = v.u + 0x7fffu + ((v.u >> 16) & 1u);  // RNE
    return (ushort_t)(r >> 16);
}

// ---------------- cast h (fp32 -> bf16) ----------------
__global__ void cast_h_kernel(const float* __restrict__ h, ushort_t* __restrict__ hb, int n4) {
    int i = blockIdx.x * blockDim.x + threadIdx.x;
    if (i < n4) {
        float4 v = ((const float4*)h)[i];
        ushort4 o;
        o.x = f2bf(v.x); o.y = f2bf(v.y); o.z = f2bf(v.z); o.w = f2bf(v.w);
        ((ushort4*)hb)[i] = o;
    }
}

// ---------------- router: sigmoid + top-8 -> dense comb[T,E] ----------------
__global__ void router_kernel(const float* __restrict__ h, const float* __restrict__ gw,
                              float* __restrict__ comb, int T) {
    int t = blockIdx.x;
    int l = threadIdx.x;
    const float* hr = h + (size_t)t * H_DIM;
    __shared__ float logits[E_NUM];
    for (int e = 0; e < E_NUM; e++) {
        const float* g = gw + e * H_DIM;
        float p = 0.f;
        #pragma unroll 8
        for (int j = l; j < H_DIM; j += 64) p += hr[j] * g[j];
        #pragma unroll
        for (int off = 32; off > 0; off >>= 1) p += __shfl_down(p, off);
        if (l == 0) logits[e] = p;
    }
    __syncthreads();
    if (l == 0) {
        float sig[E_NUM]; bool sel[E_NUM];
        #pragma unroll
        for (int e = 0; e < E_NUM; e++) { sig[e] = 1.f / (1.f + expf(-logits[e])); sel[e] = false; }
        #pragma unroll
        for (int k = 0; k < TOPK; k++) {
            int bi = 0; float bv = -1.f;
            #pragma unroll
            for (int e = 0; e < E_NUM; e++)
                if (!sel[e] && sig[e] > bv) { bv = sig[e]; bi = e; }
            sel[bi] = true;
        }
        float s = 0.f;
        #pragma unroll
        for (int e = 0; e < E_NUM; e++) if (sel[e]) s += sig[e];
        float inv = SCALE_F / (s + 1e-6f);
        #pragma unroll
        for (int e = 0; e < E_NUM; e++)
            comb[(size_t)t * E_NUM + e] = sel[e] ? sig[e] * inv : 0.f;
    }
}

// ============ FAST transpose+convert: fp32 [z][K][N] -> bf16 [z][N][K] ============
// 64(K) x 256(N) tile, 512 threads, fp32 LDS stride-65 pad.
// Reads: 1KB contiguous per row (64 lanes x float4). Writes: 64B/thread ushort8 x4.
// dual=1: second matrix (Su->Du) reuses LDS after a barrier (gate+up fused).
__global__ __launch_bounds__(512)
void transpose_cvt_kernel(const float* __restrict__ Sg, const float* __restrict__ Su,
                          ushort_t* __restrict__ Dg, ushort_t* __restrict__ Du,
                          int K, int N, size_t sStride, size_t dStride, int dual)
{
    __shared__ float lds[256][65];   // [n_local][k_local], 66.5 KB -> 2 blocks/CU

    const int z  = blockIdx.z;
    const int k0 = blockIdx.x * 64;
    const int n0 = blockIdx.y * 256;
    const int tid = threadIdx.x;
    const int rr = tid >> 6;           // 0..7  (row within 8-row pass)
    const int c4 = (tid & 63) * 4;     // col (float4 granule)
    const int n  = tid >> 1;           // 0..255 (output row)
    const int hh = (tid & 1) * 32;     // half of output row (32 floats = 64B out)

    for (int m = 0; m < 2; ++m) {
        if (m == 1 && !dual) break;
        const float* S = (m == 0 ? Sg : Su) + (size_t)z * sStride;
        ushort_t*    D = (m == 0 ? Dg : Du) + (size_t)z * dStride;

        if (m == 1) __syncthreads();   // lds reuse fence
        #pragma unroll
        for (int p = 0; p < 8; ++p) {
            int r = p * 8 + rr;
            float4 v = *(const float4*)&S[(size_t)(k0 + r) * N + n0 + c4];
            lds[c4 + 0][r] = v.x;
            lds[c4 + 1][r] = v.y;
            lds[c4 + 2][r] = v.z;
            lds[c4 + 3][r] = v.w;
        }
        __syncthreads();

        ushort_t* drow = &D[(size_t)(n0 + n) * K + k0 + hh];
        #pragma unroll
        for (int q = 0; q < 4; ++q) {
            short8 o;
            #pragma unroll
            for (int j = 0; j < 8; ++j) o[j] = (short)f2bf(lds[n][hh + q * 8 + j]);
            *(short8*)&drow[q * 8] = o;
        }
    }
}

// ================= FAST PATH: m97-style GEMMs, B pre-transposed bf16 [N,K] ============

// GEMM1: C = rowscale * silu(A@Bg^T) * (A@Bu^T), bf16 out
__global__ __launch_bounds__(256, 2)
void gemm1f_kernel(const ushort_t* __restrict__ A, int lda,
                   const ushort_t* __restrict__ Bg0, const ushort_t* __restrict__ Bu0,
                   size_t bSeg,
                   ushort_t* __restrict__ C0, size_t cSeg, int ldc,
                   const float* __restrict__ comb, int Kdim)
{
    __shared__ ushort_t Als[BM * BK];
    __shared__ ushort_t Bgs[BN * BK];
    __shared__ ushort_t Bus[BN * BK];

    int z = blockIdx.z;
    const ushort_t* Bg = Bg0 + (size_t)z * bSeg;
    const ushort_t* Bu = Bu0 + (size_t)z * bSeg;
    ushort_t* C = C0 + (size_t)z * cSeg;
    int t0 = blockIdx.x * BM, n0 = blockIdx.y * BN;
    int tid = threadIdx.x, lane = tid & 63, wid = tid >> 6;
    int wm = (wid & 1) * 64, wn = (wid >> 1) * 64;
    int quad = lane >> 4, l15 = lane & 15;

    int srow = lane >> 2;          // 0..15
    int scol = (lane & 3) * 8;     // element col (16B granules)
    int rb = wid * 32;             // wave's 32-row slab

    float4v accg[4][4], accu[4][4];
    #pragma unroll
    for (int i = 0; i < 4; i++)
        #pragma unroll
        for (int j = 0; j < 4; j++) {
            accg[i][j] = (float4v){0.f, 0.f, 0.f, 0.f};
            accu[i][j] = (float4v){0.f, 0.f, 0.f, 0.f};
        }

    const ushort_t* Ab0  = A  + (size_t)(t0 + rb + srow)      * lda  + scol;
    const ushort_t* Ab1  = A  + (size_t)(t0 + rb + 16 + srow) * lda  + scol;
    const ushort_t* Bgb0 = Bg + (size_t)(n0 + rb + srow)      * Kdim + scol;
    const ushort_t* Bgb1 = Bg + (size_t)(n0 + rb + 16 + srow) * Kdim + scol;
    const ushort_t* Bub0 = Bu + (size_t)(n0 + rb + srow)      * Kdim + scol;
    const ushort_t* Bub1 = Bu + (size_t)(n0 + rb + 16 + srow) * Kdim + scol;
    ushort_t* lA0  = &Als[rb * BK];
    ushort_t* lA1  = &Als[(rb + 16) * BK];
    ushort_t* lBg0 = &Bgs[rb * BK];
    ushort_t* lBg1 = &Bgs[(rb + 16) * BK];
    ushort_t* lBu0 = &Bus[rb * BK];
    ushort_t* lBu1 = &Bus[(rb + 16) * BK];

    for (int k0 = 0; k0 < Kdim; k0 += BK) {
        GLOAD_LDS16(Ab0 + k0,  lA0);
        GLOAD_LDS16(Ab1 + k0,  lA1);
        GLOAD_LDS16(Bgb0 + k0, lBg0);
        GLOAD_LDS16(Bgb1 + k0, lBg1);
        GLOAD_LDS16(Bub0 + k0, lBu0);
        GLOAD_LDS16(Bub1 + k0, lBu1);
        __syncthreads();

        bf16x8 af[4], bg[4], bu[4];
        #pragma unroll
        for (int i = 0; i < 4; i++)
            af[i] = *(const bf16x8*)&Als[(wm + i * 16 + l15) * BK + quad * 8];
        #pragma unroll
        for (int j = 0; j < 4; j++) {
            bg[j] = *(const bf16x8*)&Bgs[(wn + j * 16 + l15) * BK + quad * 8];
            bu[j] = *(const bf16x8*)&Bus[(wn + j * 16 + l15) * BK + quad * 8];
        }
        #pragma unroll
        for (int i = 0; i < 4; i++)
            #pragma unroll
            for (int j = 0; j < 4; j++) {
                accg[i][j] = __builtin_amdgcn_mfma_f32_16x16x32_bf16(af[i], bg[j], accg[i][j], 0, 0, 0);
                accu[i][j] = __builtin_amdgcn_mfma_f32_16x16x32_bf16(af[i], bu[j], accu[i][j], 0, 0, 0);
            }
        __syncthreads();
    }

    #pragma unroll
    for (int i = 0; i < 4; i++) {
        #pragma unroll
        for (int r = 0; r < 4; r++) {
            int t = t0 + wm + i * 16 + quad * 4 + r;
            float sc = comb ? comb[(size_t)t * E_NUM + z] : 1.f;
            #pragma unroll
            for (int j = 0; j < 4; j++) {
                float g = accg[i][j][r], u = accu[i][j][r];
                float sg = g / (1.f + __expf(-g));
                float v = sg * u * sc;
                int c = n0 + wn + j * 16 + l15;
                C[(size_t)t * ldc + c] = f2bf(v);
            }
        }
    }
}

// GEMM2: Out (=|+=|atomic+=) sum_seg A_seg @ B_seg^T, fp32 out
__global__ __launch_bounds__(256, 2)
void gemm2f_kernel(const ushort_t* __restrict__ A0, size_t aSeg, int lda,
                   const ushort_t* __restrict__ B0, size_t bSeg,
                   float* __restrict__ Out, int N,
                   int nsegPerZ, int Kper, int mode)
{
    __shared__ ushort_t Als[BM * BK];
    __shared__ ushort_t Bls[BN * BK];

    int t0 = blockIdx.x * BM, n0 = blockIdx.y * BN;
    int z = blockIdx.z;
    int tid = threadIdx.x, lane = tid & 63, wid = tid >> 6;
    int wm = (wid & 1) * 64, wn = (wid >> 1) * 64;
    int quad = lane >> 4, l15 = lane & 15;

    int srow = lane >> 2;
    int scol = (lane & 3) * 8;
    int rb = wid * 32;

    float4v acc[4][4];
    #pragma unroll
    for (int i = 0; i < 4; i++)
        #pragma unroll
        for (int j = 0; j < 4; j++) acc[i][j] = (float4v){0.f, 0.f, 0.f, 0.f};

    ushort_t* lA0 = &Als[rb * BK];
    ushort_t* lA1 = &Als[(rb + 16) * BK];
    ushort_t* lB0 = &Bls[rb * BK];
    ushort_t* lB1 = &Bls[(rb + 16) * BK];

    for (int s = 0; s < nsegPerZ; s++) {
        int seg = z * nsegPerZ + s;
        const ushort_t* A = A0 + (size_t)seg * aSeg;
        const ushort_t* B = B0 + (size_t)seg * bSeg;
        const ushort_t* Ab0 = A + (size_t)(t0 + rb + srow)      * lda  + scol;
        const ushort_t* Ab1 = A + (size_t)(t0 + rb + 16 + srow) * lda  + scol;
        const ushort_t* Bb0 = B + (size_t)(n0 + rb + srow)      * Kper + scol;
        const ushort_t* Bb1 = B + (size_t)(n0 + rb + 16 + srow) * Kper + scol;

        for (int k0 = 0; k0 < Kper; k0 += BK) {
            GLOAD_LDS16(Ab0 + k0, lA0);
            GLOAD_LDS16(Ab1 + k0, lA1);
            GLOAD_LDS16(Bb0 + k0, lB0);
            GLOAD_LDS16(Bb1 + k0, lB1);
            __syncthreads();

            bf16x8 af[4], bf[4];
            #pragma unroll
            for (int i = 0; i < 4; i++)
                af[i] = *(const bf16x8*)&Als[(wm + i * 16 + l15) * BK + quad * 8];
            #pragma unroll
            for (int j = 0; j < 4; j++)
                bf[j] = *(const bf16x8*)&Bls[(wn + j * 16 + l15) * BK + quad * 8];
            #pragma unroll
            for (int i = 0; i < 4; i++)
                #pragma unroll
                for (int j = 0; j < 4; j++)
                    acc[i][j] = __builtin_amdgcn_mfma_f32_16x16x32_bf16(af[i], bf[j], acc[i][j], 0, 0, 0);
            __syncthreads();
        }
    }

    #pragma unroll
    for (int i = 0; i < 4; i++) {
        #pragma unroll
        for (int r = 0; r < 4; r++) {
            int t = t0 + wm + i * 16 + quad * 4 + r;
            #pragma unroll
            for (int j = 0; j < 4; j++) {
                int c = n0 + wn + j * 16 + l15;
                size_t idx = (size_t)t * N + c;
                float v = acc[i][j][r];
                if (mode == 0) Out[idx] = v;
                else if (mode == 1) Out[idx] += v;
                else atomicAdd(&Out[idx], v);
            }
        }
    }
}

// ================= FALLBACK PATH (round-1 kernels, ws-lean) ==========================

__global__ __launch_bounds__(256)
void gemm1_kernel(const ushort_t* __restrict__ A, int lda,
                  const float* __restrict__ Bg0, const float* __restrict__ Bu0,
                  size_t bSeg, int ldb,
                  ushort_t* __restrict__ C0, size_t cSeg, int ldc,
                  const float* __restrict__ comb, int Kdim)
{
    __shared__ ushort_t Als[BM * LDSP];
    __shared__ ushort_t Bgs[BN * LDSP];
    __shared__ ushort_t Bus[BN * LDSP];

    int z = blockIdx.z;
    const float* Bg = Bg0 + (size_t)z * bSeg;
    const float* Bu = Bu0 + (size_t)z * bSeg;
    ushort_t* C = C0 + (size_t)z * cSeg;

    int t0 = blockIdx.x * BM;
    int n0 = blockIdx.y * BN;
    int tid = threadIdx.x;
    int lane = tid & 63, wid = tid >> 6;
    int wm = (wid & 1) * 64, wn = (wid >> 1) * 64;
    int quad = lane >> 4, l15 = lane & 15;

    float4v accg[4][4], accu[4][4];
    #pragma unroll
    for (int i = 0; i < 4; i++)
        #pragma unroll
        for (int j = 0; j < 4; j++) {
            accg[i][j] = (float4v){0.f, 0.f, 0.f, 0.f};
            accu[i][j] = (float4v){0.f, 0.f, 0.f, 0.f};
        }

    int a_r  = tid >> 2, a_oc = tid & 3;
    int b_ko = (tid >> 4) & 3;
    int b_n  = 2 * ((tid & 15) + ((tid >> 6) << 4));

    for (int k0 = 0; k0 < Kdim; k0 += BK) {
        __syncthreads();
        {
            const ushort_t* s0 = A + (size_t)(t0 + a_r) * lda + k0 + a_oc * 8;
            *(short8*)&Als[a_r * LDSP + a_oc * 8] = *(const short8*)s0;
            const ushort_t* s1 = A + (size_t)(t0 + a_r + 64) * lda + k0 + a_oc * 8;
            *(short8*)&Als[(a_r + 64) * LDSP + a_oc * 8] = *(const short8*)s1;
        }
        {
            short8 g0, g1, u0, u1;
            #pragma unroll
            for (int j = 0; j < 8; j++) {
                size_t roff = (size_t)(k0 + b_ko * 8 + j) * ldb + n0 + b_n;
                float2 vg = *(const float2*)&Bg[roff];
                float2 vu = *(const float2*)&Bu[roff];
                g0[j] = (short)f2bf(vg.x); g1[j] = (short)f2bf(vg.y);
                u0[j] = (short)f2bf(vu.x); u1[j] = (short)f2bf(vu.y);
            }
            *(short8*)&Bgs[b_n * LDSP + b_ko * 8]       = g0;
            *(short8*)&Bgs[(b_n + 1) * LDSP + b_ko * 8] = g1;
            *(short8*)&Bus[b_n * LDSP + b_ko * 8]       = u0;
            *(short8*)&Bus[(b_n + 1) * LDSP + b_ko * 8] = u1;
        }
        __syncthreads();

        bf16x8 af[4], bg[4], bu[4];
        #pragma unroll
        for (int i = 0; i < 4; i++)
            af[i] = *(const bf16x8*)&Als[(wm + i * 16 + l15) * LDSP + quad * 8];
        #pragma unroll
        for (int j = 0; j < 4; j++) {
            bg[j] = *(const bf16x8*)&Bgs[(wn + j * 16 + l15) * LDSP + quad * 8];
            bu[j] = *(const bf16x8*)&Bus[(wn + j * 16 + l15) * LDSP + quad * 8];
        }
        #pragma unroll
        for (int i = 0; i < 4; i++)
            #pragma unroll
            for (int j = 0; j < 4; j++) {
                accg[i][j] = __builtin_amdgcn_mfma_f32_16x16x32_bf16(af[i], bg[j], accg[i][j], 0, 0, 0);
                accu[i][j] = __builtin_amdgcn_mfma_f32_16x16x32_bf16(af[i], bu[j], accu[i][j], 0, 0, 0);
            }
    }

    #pragma unroll
    for (int i = 0; i < 4; i++) {
        #pragma unroll
        for (int r = 0; r < 4; r++) {
            int t = t0 + wm + i * 16 + quad * 4 + r;
            float sc = comb ? comb[(size_t)t * E_NUM + z] : 1.f;
            #pragma unroll
            for (int j = 0; j < 4; j++) {
                float g = accg[i][j][r], u = accu[i][j][r];
                float sg = g / (1.f + __expf(-g));
                float v = sg * u * sc;
                int c = n0 + wn + j * 16 + l15;
                C[(size_t)t * ldc + c] = f2bf(v);
            }
        }
    }
}

__global__ __launch_bounds__(256)
void gemm2_kernel(const ushort_t* __restrict__ A0, size_t aSeg, int lda,
                  const float* __restrict__ B0, size_t bSeg, int ldb,
                  float* __restrict__ Out, int N,
                  int nseg, int Kper, int accum)
{
    __shared__ ushort_t Als[BM * LDSP];
    __shared__ ushort_t Bls[BN * LDSP];

    int t0 = blockIdx.x * BM;
    int n0 = blockIdx.y * BN;
    int tid = threadIdx.x;
    int lane = tid & 63, wid = tid >> 6;
    int wm = (wid & 1) * 64, wn = (wid >> 1) * 64;
    int quad = lane >> 4, l15 = lane & 15;

    float4v acc[4][4];
    #pragma unroll
    for (int i = 0; i < 4; i++)
        #pragma unroll
        for (int j = 0; j < 4; j++) acc[i][j] = (float4v){0.f, 0.f, 0.f, 0.f};

    int a_r  = tid >> 2, a_oc = tid & 3;
    int b_ko = (tid >> 4) & 3;
    int b_n  = 2 * ((tid & 15) + ((tid >> 6) << 4));

    for (int seg = 0; seg < nseg; seg++) {
        const ushort_t* A = A0 + (size_t)seg * aSeg;
        const float*    B = B0 + (size_t)seg * bSeg;
        for (int k0 = 0; k0 < Kper; k0 += BK) {
            __syncthreads();
            {
                const ushort_t* s0 = A + (size_t)(t0 + a_r) * lda + k0 + a_oc * 8;
                *(short8*)&Als[a_r * LDSP + a_oc * 8] = *(const short8*)s0;
                const ushort_t* s1 = A + (size_t)(t0 + a_r + 64) * lda + k0 + a_oc * 8;
                *(short8*)&Als[(a_r + 64) * LDSP + a_oc * 8] = *(const short8*)s1;
            }
            {
                short8 r0, r1;
                #pragma unroll
                for (int j = 0; j < 8; j++) {
                    size_t roff = (size_t)(k0 + b_ko * 8 + j) * ldb + n0 + b_n;
                    float2 v = *(const float2*)&B[roff];
                    r0[j] = (short)f2bf(v.x); r1[j] = (short)f2bf(v.y);
                }
                *(short8*)&Bls[b_n * LDSP + b_ko * 8]       = r0;
                *(short8*)&Bls[(b_n + 1) * LDSP + b_ko * 8] = r1;
            }
            __syncthreads();

            bf16x8 af[4], bf[4];
            #pragma unroll
            for (int i = 0; i < 4; i++)
                af[i] = *(const bf16x8*)&Als[(wm + i * 16 + l15) * LDSP + quad * 8];
            #pragma unroll
            for (int j = 0; j < 4; j++)
                bf[j] = *(const bf16x8*)&Bls[(wn + j * 16 + l15) * LDSP + quad * 8];
            #pragma unroll
            for (int i = 0; i < 4; i++)
                #pragma unroll
                for (int j = 0; j < 4; j++)
                    acc[i][j] = __builtin_amdgcn_mfma_f32_16x16x32_bf16(af[i], bf[j], acc[i][j], 0, 0, 0);
        }
    }

    #pragma unroll
    for (int i = 0; i < 4; i++) {
        #pragma unroll
        for (int r = 0; r < 4; r++) {
            int t = t0 + wm + i * 16 + quad * 4 + r;
            #pragma unroll
            for (int j = 0; j < 4; j++) {
                int c = n0 + wn + j * 16 + l15;
                size_t idx = (size_t)t * N + c;
                float v = acc[i][j][r];
                if (accum) Out[idx] += v; else Out[idx] = v;
            }
        }
    }
}

// =====================================================================================

extern "C" void kernel_launch(void* const* d_in, const int* in_sizes, int n_in,
                              void* d_out, int out_size, void* d_ws, size_t ws_size,
                              hipStream_t stream) {
    const float* h      = (const float*)d_in[0];
    const float* gate_w = (const float*)d_in[1];
    const float* Wg     = (const float*)d_in[2];
    const float* Wu     = (const float*)d_in[3];
    const float* Wd     = (const float*)d_in[4];
    const float* sWg    = (const float*)d_in[5];
    const float* sWu    = (const float*)d_in[6];
    const float* sWd    = (const float*)d_in[7];
    float* out = (float*)d_out;
    int T = in_sizes[0] / H_DIM;
    (void)n_in; (void)out_size;

    char* ws = (char*)d_ws;
    size_t off = 0;
    auto alloc = [&](size_t bytes) -> void* {
        void* p = ws + off;
        off = (off + bytes + 255) & ~(size_t)255;
        return p;
    };
    ushort_t* h_bf  = (ushort_t*)alloc((size_t)T * H_DIM * 2);
    float*    comb  = (float*)   alloc((size_t)T * E_NUM * 4);
    ushort_t* act_s = (ushort_t*)alloc((size_t)T * IS_DIM * 2);
    ushort_t* act_r = (ushort_t*)alloc((size_t)E_NUM * T * IM_DIM * 2);
    // fast-path weight buffers (reused over launch sequence)
    ushort_t* bufS1 = (ushort_t*)alloc((size_t)IS_DIM * H_DIM * 2);          // 8 MB
    ushort_t* bufS2 = (ushort_t*)alloc((size_t)IS_DIM * H_DIM * 2);          // 8 MB
    ushort_t* bufW1 = (ushort_t*)alloc((size_t)E_NUM * IM_DIM * H_DIM * 2);  // 64 MB
    ushort_t* bufW2 = (ushort_t*)alloc((size_t)E_NUM * IM_DIM * H_DIM * 2);  // 64 MB
    size_t need = off;

    int n4 = T * H_DIM / 4;
    cast_h_kernel<<<(n4 + 255) / 256, 256, 0, stream>>>(h, h_bf, n4);
    router_kernel<<<T, 64, 0, stream>>>(h, gate_w, comb, T);

    if (ws_size >= need) {
        // ---- fast path: pre-transposed bf16 weights + global_load_lds GEMMs ----
        // shared gate+up weights (dual): [H][IS] -> [IS][H]
        transpose_cvt_kernel<<<dim3(H_DIM / 64, IS_DIM / 256, 1), 512, 0, stream>>>(
            sWg, sWu, bufS1, bufS2, H_DIM, IS_DIM, 0, 0, 1);
        gemm1f_kernel<<<dim3(T / BM, IS_DIM / BN, 1), 256, 0, stream>>>(
            h_bf, H_DIM, bufS1, bufS2, 0, act_s, 0, IS_DIM, nullptr, H_DIM);

        // routed gate+up weights (dual): [E][H][IM] -> [E][IM][H]
        transpose_cvt_kernel<<<dim3(H_DIM / 64, IM_DIM / 256, E_NUM), 512, 0, stream>>>(
            Wg, Wu, bufW1, bufW2, H_DIM, IM_DIM,
            (size_t)H_DIM * IM_DIM, (size_t)IM_DIM * H_DIM, 1);
        gemm1f_kernel<<<dim3(T / BM, IM_DIM / BN, E_NUM), 256, 0, stream>>>(
            h_bf, H_DIM, bufW1, bufW2, (size_t)IM_DIM * H_DIM,
            act_r, (size_t)T * IM_DIM, IM_DIM, comb, H_DIM);

        // shared down weight: [IS][H] -> [H][IS]  (reuse bufS1 after gemm1f shared)
        transpose_cvt_kernel<<<dim3(IS_DIM / 64, H_DIM / 256, 1), 512, 0, stream>>>(
            sWd, nullptr, bufS1, nullptr, IS_DIM, H_DIM, 0, 0, 0);
        gemm2f_kernel<<<dim3(T / BM, H_DIM / BN, 1), 256, 0, stream>>>(
            act_s, 0, IS_DIM, bufS1, 0, out, H_DIM, 1, IS_DIM, 0);

        // routed down weight: [E][IM][H] -> [E][H][IM]  (reuse bufW1 after gemm1f routed)
        transpose_cvt_kernel<<<dim3(IM_DIM / 64, H_DIM / 256, E_NUM), 512, 0, stream>>>(
            Wd, nullptr, bufW1, nullptr, IM_DIM, H_DIM,
            (size_t)IM_DIM * H_DIM, (size_t)H_DIM * IM_DIM, 0);
        gemm2f_kernel<<<dim3(T / BM, H_DIM / BN, 2), 256, 0, stream>>>(
            act_r, (size_t)T * IM_DIM, IM_DIM, bufW1, (size_t)H_DIM * IM_DIM,
            out, H_DIM, E_NUM / 2, IM_DIM, 2);
    } else {
        // ---- fallback: round-1 path (~80 MB ws) ----
        gemm1_kernel<<<dim3(T / BM, IS_DIM / BN, 1), 256, 0, stream>>>(
            h_bf, H_DIM, sWg, sWu, 0, IS_DIM, act_s, 0, IS_DIM, nullptr, H_DIM);
        gemm1_kernel<<<dim3(T / BM, IM_DIM / BN, E_NUM), 256, 0, stream>>>(
            h_bf, H_DIM, Wg, Wu, (size_t)H_DIM * IM_DIM, IM_DIM,
            act_r, (size_t)T * IM_DIM, IM_DIM, comb, H_DIM);
        gemm2_kernel<<<dim3(T / BM, H_DIM / BN, 1), 256, 0, stream>>>(
            act_s, 0, IS_DIM, sWd, 0, H_DIM, out, H_DIM, 1, IS_DIM, 0);
        gemm2_kernel<<<dim3(T / BM, H_DIM / BN, 1), 256, 0, stream>>>(
            act_r, (size_t)T * IM_DIM, IM_DIM, Wd, (size_t)IM_DIM * H_DIM, H_DIM,
            out, H_DIM, E_NUM, IM_DIM, 1);
    }
}

// Round 4
// 1110.598 us; speedup vs baseline: 1.1555x; 1.0394x over previous
//
#include <hip/hip_runtime.h>
#include <hip/hip_bf16.h>
#include <stdint.h>

#define H_DIM  2048
#define IM_DIM 1024
#define E_NUM  16
#define TOPK   8
#define IS_DIM 2048
#define SCALE_F 2.5f

#define BM 128
#define BN 128
#define BK 32
#define LDSP 40   // fallback-path padded LDS row stride

typedef __attribute__((ext_vector_type(8))) short   short8;
typedef __attribute__((ext_vector_type(8))) __bf16  bf16x8;
typedef __attribute__((ext_vector_type(4))) float   float4v;
typedef unsigned short ushort_t;

// async global->LDS, 16B per lane; LDS dest = wave-uniform base + lane*16
#define GLOAD_LDS16(gp, lp) \
    __builtin_amdgcn_global_load_lds((__attribute__((address_space(1))) void*)(gp), \
                                     (__attribute__((address_space(3))) void*)(lp), 16, 0, 0)

static __device__ __forceinline__ ushort_t f2bf(float x) {
    union { float f; uint32_t u; } v; v.f = x;
    uint32_t r = v.u + 0x7fffu + ((v.u >> 16) & 1u);  // RNE
    return (ushort_t)(r >> 16);
}

// ---------------- cast h (fp32 -> bf16) + zero out (same index space) ----------------
__global__ void cast_zero_kernel(const float* __restrict__ h, ushort_t* __restrict__ hb,
                                 float4* __restrict__ outz, int n4) {
    int i = blockIdx.x * blockDim.x + threadIdx.x;
    if (i < n4) {
        float4 v = ((const float4*)h)[i];
        ushort4 o;
        o.x = f2bf(v.x); o.y = f2bf(v.y); o.z = f2bf(v.z); o.w = f2bf(v.w);
        ((ushort4*)hb)[i] = o;
        outz[i] = make_float4(0.f, 0.f, 0.f, 0.f);
    }
}

// ---------------- router: sigmoid + top-8 -> dense comb[T,E] ----------------
__global__ void router_kernel(const float* __restrict__ h, const float* __restrict__ gw,
                              float* __restrict__ comb, int T) {
    int t = blockIdx.x;
    int l = threadIdx.x;
    const float* hr = h + (size_t)t * H_DIM;
    __shared__ float logits[E_NUM];
    for (int e = 0; e < E_NUM; e++) {
        const float* g = gw + e * H_DIM;
        float p = 0.f;
        #pragma unroll 8
        for (int j = l; j < H_DIM; j += 64) p += hr[j] * g[j];
        #pragma unroll
        for (int off = 32; off > 0; off >>= 1) p += __shfl_down(p, off);
        if (l == 0) logits[e] = p;
    }
    __syncthreads();
    if (l == 0) {
        float sig[E_NUM]; bool sel[E_NUM];
        #pragma unroll
        for (int e = 0; e < E_NUM; e++) { sig[e] = 1.f / (1.f + expf(-logits[e])); sel[e] = false; }
        #pragma unroll
        for (int k = 0; k < TOPK; k++) {
            int bi = 0; float bv = -1.f;
            #pragma unroll
            for (int e = 0; e < E_NUM; e++)
                if (!sel[e] && sig[e] > bv) { bv = sig[e]; bi = e; }
            sel[bi] = true;
        }
        float s = 0.f;
        #pragma unroll
        for (int e = 0; e < E_NUM; e++) if (sel[e]) s += sig[e];
        float inv = SCALE_F / (s + 1e-6f);
        #pragma unroll
        for (int e = 0; e < E_NUM; e++)
            comb[(size_t)t * E_NUM + e] = sel[e] ? sig[e] * inv : 0.f;
    }
}

// ============ transpose+convert body: fp32 [K][N-tile] -> bf16 [N][K] ============
// 64(K) x 256(N) tile, 512 threads, fp32 LDS stride-65 pad.
// lds passed in so dual-matrix callers reuse one allocation.
static __device__ __forceinline__
void transpose_body(const float* __restrict__ S, ushort_t* __restrict__ D,
                    int srcLd, int dstLd, int k0, int n0, int tid,
                    float (*lds)[65])
{
    const int rr = tid >> 6;           // 0..7  (row within 8-row pass)
    const int c4 = (tid & 63) * 4;     // col (float4 granule)
    const int n  = tid >> 1;           // 0..255 (output row)
    const int hh = (tid & 1) * 32;     // half of output row (32 bf16 = 64B out)

    #pragma unroll
    for (int p = 0; p < 8; ++p) {
        int r = p * 8 + rr;
        float4 v = *(const float4*)&S[(size_t)(k0 + r) * srcLd + n0 + c4];
        lds[c4 + 0][r] = v.x;
        lds[c4 + 1][r] = v.y;
        lds[c4 + 2][r] = v.z;
        lds[c4 + 3][r] = v.w;
    }
    __syncthreads();

    ushort_t* drow = &D[(size_t)(n0 + n) * dstLd + k0 + hh];
    #pragma unroll
    for (int q = 0; q < 4; ++q) {
        short8 o;
        #pragma unroll
        for (int j = 0; j < 8; ++j) o[j] = (short)f2bf(lds[n][hh + q * 8 + j]);
        *(short8*)&drow[q * 8] = o;
    }
}

// gate+up transposes, all 18 segments in one launch.
// z<16: routed Wg/Wu[z] [H][IM] -> bufW1/2[z] [IM][H]
// z>=16: shared sWg/sWu column-slice s=z-16 [H][IM-cols] -> bufS1/2 rows s*IM [IM][H]
__global__ __launch_bounds__(512)
void transpose_gu_kernel(const float* __restrict__ Wg, const float* __restrict__ Wu,
                         const float* __restrict__ sWg, const float* __restrict__ sWu,
                         ushort_t* __restrict__ bufW1, ushort_t* __restrict__ bufW2,
                         ushort_t* __restrict__ bufS1, ushort_t* __restrict__ bufS2)
{
    __shared__ float lds[256][65];
    const int z = blockIdx.z;
    const int k0 = blockIdx.x * 64;        // over H
    const int n0 = blockIdx.y * 256;       // over IM
    const int tid = threadIdx.x;

    const float* Sg; const float* Su; ushort_t* Dg; ushort_t* Du; int srcLd;
    if (z < E_NUM) {
        Sg = Wg + (size_t)z * H_DIM * IM_DIM;
        Su = Wu + (size_t)z * H_DIM * IM_DIM;
        Dg = bufW1 + (size_t)z * IM_DIM * H_DIM;
        Du = bufW2 + (size_t)z * IM_DIM * H_DIM;
        srcLd = IM_DIM;
    } else {
        int s = z - E_NUM;
        Sg = sWg + (size_t)s * IM_DIM;     // column slice
        Su = sWu + (size_t)s * IM_DIM;
        Dg = bufS1 + (size_t)s * IM_DIM * H_DIM;
        Du = bufS2 + (size_t)s * IM_DIM * H_DIM;
        srcLd = IS_DIM;
    }
    transpose_body(Sg, Dg, srcLd, H_DIM, k0, n0, tid, lds);
    __syncthreads();
    transpose_body(Su, Du, srcLd, H_DIM, k0, n0, tid, lds);
}

// down transposes, all 18 segments in one launch (into buffers freed by gemm1).
// z<16: Wd[z] [IM][H] -> bufW2[z] [H][IM]   (dstLd = IM)
// z>=16: sWd row-slice s [IM][H] -> bufS2 [H][IS] columns s*IM (dstLd = IS)
__global__ __launch_bounds__(512)
void transpose_d_kernel(const float* __restrict__ Wd, const float* __restrict__ sWd,
                        ushort_t* __restrict__ bufW2, ushort_t* __restrict__ bufS2)
{
    __shared__ float lds[256][65];
    const int z = blockIdx.z;
    const int k0 = blockIdx.x * 64;        // over IM (1024)
    const int n0 = blockIdx.y * 256;       // over H (2048)
    const int tid = threadIdx.x;

    const float* S; ushort_t* D; int dstLd;
    if (z < E_NUM) {
        S = Wd + (size_t)z * IM_DIM * H_DIM;
        D = bufW2 + (size_t)z * H_DIM * IM_DIM;
        dstLd = IM_DIM;
    } else {
        int s = z - E_NUM;
        S = sWd + (size_t)s * IM_DIM * H_DIM;   // rows s*IM .. of [IS][H]
        D = bufS2 + (size_t)s * IM_DIM;         // columns s*IM of [H][IS]
        dstLd = IS_DIM;
    }
    transpose_body(S, D, H_DIM, dstLd, k0, n0, tid, lds);
}

// ================= unified GEMM1: 18 segments (16 routed + 2 shared slices) ==========
// C = rowscale * silu(A@Bg^T) * (A@Bu^T), bf16 out
__global__ __launch_bounds__(256, 2)
void gemm1u_kernel(const ushort_t* __restrict__ A,
                   const ushort_t* __restrict__ bufW1, const ushort_t* __restrict__ bufW2,
                   const ushort_t* __restrict__ bufS1, const ushort_t* __restrict__ bufS2,
                   ushort_t* __restrict__ act_r, ushort_t* __restrict__ act_s,
                   const float* __restrict__ comb, int T)
{
    __shared__ ushort_t Als[BM * BK];
    __shared__ ushort_t Bgs[BN * BK];
    __shared__ ushort_t Bus[BN * BK];

    const int z = blockIdx.z;
    const ushort_t* Bg; const ushort_t* Bu; ushort_t* C; int ldc; bool useComb;
    if (z < E_NUM) {
        Bg = bufW1 + (size_t)z * IM_DIM * H_DIM;
        Bu = bufW2 + (size_t)z * IM_DIM * H_DIM;
        C  = act_r + (size_t)z * T * IM_DIM;
        ldc = IM_DIM; useComb = true;
    } else {
        int s = z - E_NUM;
        Bg = bufS1 + (size_t)s * IM_DIM * H_DIM;
        Bu = bufS2 + (size_t)s * IM_DIM * H_DIM;
        C  = act_s + (size_t)s * IM_DIM;
        ldc = IS_DIM; useComb = false;
    }

    int t0 = blockIdx.x * BM, n0 = blockIdx.y * BN;
    int tid = threadIdx.x, lane = tid & 63, wid = tid >> 6;
    int wm = (wid & 1) * 64, wn = (wid >> 1) * 64;
    int quad = lane >> 4, l15 = lane & 15;

    int srow = lane >> 2;          // 0..15
    int scol = (lane & 3) * 8;     // element col (16B granules)
    int rb = wid * 32;             // wave's 32-row slab

    float4v accg[4][4], accu[4][4];
    #pragma unroll
    for (int i = 0; i < 4; i++)
        #pragma unroll
        for (int j = 0; j < 4; j++) {
            accg[i][j] = (float4v){0.f, 0.f, 0.f, 0.f};
            accu[i][j] = (float4v){0.f, 0.f, 0.f, 0.f};
        }

    const ushort_t* Ab0  = A  + (size_t)(t0 + rb + srow)      * H_DIM + scol;
    const ushort_t* Ab1  = A  + (size_t)(t0 + rb + 16 + srow) * H_DIM + scol;
    const ushort_t* Bgb0 = Bg + (size_t)(n0 + rb + srow)      * H_DIM + scol;
    const ushort_t* Bgb1 = Bg + (size_t)(n0 + rb + 16 + srow) * H_DIM + scol;
    const ushort_t* Bub0 = Bu + (size_t)(n0 + rb + srow)      * H_DIM + scol;
    const ushort_t* Bub1 = Bu + (size_t)(n0 + rb + 16 + srow) * H_DIM + scol;
    ushort_t* lA0  = &Als[rb * BK];
    ushort_t* lA1  = &Als[(rb + 16) * BK];
    ushort_t* lBg0 = &Bgs[rb * BK];
    ushort_t* lBg1 = &Bgs[(rb + 16) * BK];
    ushort_t* lBu0 = &Bus[rb * BK];
    ushort_t* lBu1 = &Bus[(rb + 16) * BK];

    for (int k0 = 0; k0 < H_DIM; k0 += BK) {
        GLOAD_LDS16(Ab0 + k0,  lA0);
        GLOAD_LDS16(Ab1 + k0,  lA1);
        GLOAD_LDS16(Bgb0 + k0, lBg0);
        GLOAD_LDS16(Bgb1 + k0, lBg1);
        GLOAD_LDS16(Bub0 + k0, lBu0);
        GLOAD_LDS16(Bub1 + k0, lBu1);
        __syncthreads();

        bf16x8 af[4], bg[4], bu[4];
        #pragma unroll
        for (int i = 0; i < 4; i++)
            af[i] = *(const bf16x8*)&Als[(wm + i * 16 + l15) * BK + quad * 8];
        #pragma unroll
        for (int j = 0; j < 4; j++) {
            bg[j] = *(const bf16x8*)&Bgs[(wn + j * 16 + l15) * BK + quad * 8];
            bu[j] = *(const bf16x8*)&Bus[(wn + j * 16 + l15) * BK + quad * 8];
        }
        #pragma unroll
        for (int i = 0; i < 4; i++)
            #pragma unroll
            for (int j = 0; j < 4; j++) {
                accg[i][j] = __builtin_amdgcn_mfma_f32_16x16x32_bf16(af[i], bg[j], accg[i][j], 0, 0, 0);
                accu[i][j] = __builtin_amdgcn_mfma_f32_16x16x32_bf16(af[i], bu[j], accu[i][j], 0, 0, 0);
            }
        __syncthreads();
    }

    #pragma unroll
    for (int i = 0; i < 4; i++) {
        #pragma unroll
        for (int r = 0; r < 4; r++) {
            int t = t0 + wm + i * 16 + quad * 4 + r;
            float sc = useComb ? comb[(size_t)t * E_NUM + z] : 1.f;
            #pragma unroll
            for (int j = 0; j < 4; j++) {
                float g = accg[i][j][r], u = accu[i][j][r];
                float sg = g / (1.f + __expf(-g));
                float v = sg * u * sc;
                int c = n0 + wn + j * 16 + l15;
                C[(size_t)t * ldc + c] = f2bf(v);
            }
        }
    }
}

// ================= unified GEMM2: Out += sum over 18 segments (atomic) ===============
__global__ __launch_bounds__(256, 2)
void gemm2u_kernel(const ushort_t* __restrict__ act_r, const ushort_t* __restrict__ act_s,
                   const ushort_t* __restrict__ bufW2, const ushort_t* __restrict__ bufS2,
                   float* __restrict__ Out, int T, int nsegPerZ)
{
    __shared__ ushort_t Als[BM * BK];
    __shared__ ushort_t Bls[BN * BK];

    int t0 = blockIdx.x * BM, n0 = blockIdx.y * BN;
    int z = blockIdx.z;
    int tid = threadIdx.x, lane = tid & 63, wid = tid >> 6;
    int wm = (wid & 1) * 64, wn = (wid >> 1) * 64;
    int quad = lane >> 4, l15 = lane & 15;

    int srow = lane >> 2;
    int scol = (lane & 3) * 8;
    int rb = wid * 32;

    float4v acc[4][4];
    #pragma unroll
    for (int i = 0; i < 4; i++)
        #pragma unroll
        for (int j = 0; j < 4; j++) acc[i][j] = (float4v){0.f, 0.f, 0.f, 0.f};

    ushort_t* lA0 = &Als[rb * BK];
    ushort_t* lA1 = &Als[(rb + 16) * BK];
    ushort_t* lB0 = &Bls[rb * BK];
    ushort_t* lB1 = &Bls[(rb + 16) * BK];

    for (int s = 0; s < nsegPerZ; s++) {
        int seg = z * nsegPerZ + s;
        const ushort_t* A; const ushort_t* B; int lda, ldb;
        if (seg < E_NUM) {
            A = act_r + (size_t)seg * T * IM_DIM;  lda = IM_DIM;
            B = bufW2 + (size_t)seg * H_DIM * IM_DIM; ldb = IM_DIM;
        } else {
            int s2 = seg - E_NUM;
            A = act_s + (size_t)s2 * IM_DIM;  lda = IS_DIM;
            B = bufS2 + (size_t)s2 * IM_DIM;  ldb = IS_DIM;
        }
        const ushort_t* Ab0 = A + (size_t)(t0 + rb + srow)      * lda + scol;
        const ushort_t* Ab1 = A + (size_t)(t0 + rb + 16 + srow) * lda + scol;
        const ushort_t* Bb0 = B + (size_t)(n0 + rb + srow)      * ldb + scol;
        const ushort_t* Bb1 = B + (size_t)(n0 + rb + 16 + srow) * ldb + scol;

        for (int k0 = 0; k0 < IM_DIM; k0 += BK) {
            GLOAD_LDS16(Ab0 + k0, lA0);
            GLOAD_LDS16(Ab1 + k0, lA1);
            GLOAD_LDS16(Bb0 + k0, lB0);
            GLOAD_LDS16(Bb1 + k0, lB1);
            __syncthreads();

            bf16x8 af[4], bf[4];
            #pragma unroll
            for (int i = 0; i < 4; i++)
                af[i] = *(const bf16x8*)&Als[(wm + i * 16 + l15) * BK + quad * 8];
            #pragma unroll
            for (int j = 0; j < 4; j++)
                bf[j] = *(const bf16x8*)&Bls[(wn + j * 16 + l15) * BK + quad * 8];
            #pragma unroll
            for (int i = 0; i < 4; i++)
                #pragma unroll
                for (int j = 0; j < 4; j++)
                    acc[i][j] = __builtin_amdgcn_mfma_f32_16x16x32_bf16(af[i], bf[j], acc[i][j], 0, 0, 0);
            __syncthreads();
        }
    }

    #pragma unroll
    for (int i = 0; i < 4; i++) {
        #pragma unroll
        for (int r = 0; r < 4; r++) {
            int t = t0 + wm + i * 16 + quad * 4 + r;
            #pragma unroll
            for (int j = 0; j < 4; j++) {
                int c = n0 + wn + j * 16 + l15;
                atomicAdd(&Out[(size_t)t * H_DIM + c], acc[i][j][r]);
            }
        }
    }
}

// ================= FALLBACK PATH (round-1 kernels, ws-lean) ==========================

__global__ __launch_bounds__(256)
void gemm1_kernel(const ushort_t* __restrict__ A, int lda,
                  const float* __restrict__ Bg0, const float* __restrict__ Bu0,
                  size_t bSeg, int ldb,
                  ushort_t* __restrict__ C0, size_t cSeg, int ldc,
                  const float* __restrict__ comb, int Kdim)
{
    __shared__ ushort_t Als[BM * LDSP];
    __shared__ ushort_t Bgs[BN * LDSP];
    __shared__ ushort_t Bus[BN * LDSP];

    int z = blockIdx.z;
    const float* Bg = Bg0 + (size_t)z * bSeg;
    const float* Bu = Bu0 + (size_t)z * bSeg;
    ushort_t* C = C0 + (size_t)z * cSeg;

    int t0 = blockIdx.x * BM;
    int n0 = blockIdx.y * BN;
    int tid = threadIdx.x;
    int lane = tid & 63, wid = tid >> 6;
    int wm = (wid & 1) * 64, wn = (wid >> 1) * 64;
    int quad = lane >> 4, l15 = lane & 15;

    float4v accg[4][4], accu[4][4];
    #pragma unroll
    for (int i = 0; i < 4; i++)
        #pragma unroll
        for (int j = 0; j < 4; j++) {
            accg[i][j] = (float4v){0.f, 0.f, 0.f, 0.f};
            accu[i][j] = (float4v){0.f, 0.f, 0.f, 0.f};
        }

    int a_r  = tid >> 2, a_oc = tid & 3;
    int b_ko = (tid >> 4) & 3;
    int b_n  = 2 * ((tid & 15) + ((tid >> 6) << 4));

    for (int k0 = 0; k0 < Kdim; k0 += BK) {
        __syncthreads();
        {
            const ushort_t* s0 = A + (size_t)(t0 + a_r) * lda + k0 + a_oc * 8;
            *(short8*)&Als[a_r * LDSP + a_oc * 8] = *(const short8*)s0;
            const ushort_t* s1 = A + (size_t)(t0 + a_r + 64) * lda + k0 + a_oc * 8;
            *(short8*)&Als[(a_r + 64) * LDSP + a_oc * 8] = *(const short8*)s1;
        }
        {
            short8 g0, g1, u0, u1;
            #pragma unroll
            for (int j = 0; j < 8; j++) {
                size_t roff = (size_t)(k0 + b_ko * 8 + j) * ldb + n0 + b_n;
                float2 vg = *(const float2*)&Bg[roff];
                float2 vu = *(const float2*)&Bu[roff];
                g0[j] = (short)f2bf(vg.x); g1[j] = (short)f2bf(vg.y);
                u0[j] = (short)f2bf(vu.x); u1[j] = (short)f2bf(vu.y);
            }
            *(short8*)&Bgs[b_n * LDSP + b_ko * 8]       = g0;
            *(short8*)&Bgs[(b_n + 1) * LDSP + b_ko * 8] = g1;
            *(short8*)&Bus[b_n * LDSP + b_ko * 8]       = u0;
            *(short8*)&Bus[(b_n + 1) * LDSP + b_ko * 8] = u1;
        }
        __syncthreads();

        bf16x8 af[4], bg[4], bu[4];
        #pragma unroll
        for (int i = 0; i < 4; i++)
            af[i] = *(const bf16x8*)&Als[(wm + i * 16 + l15) * LDSP + quad * 8];
        #pragma unroll
        for (int j = 0; j < 4; j++) {
            bg[j] = *(const bf16x8*)&Bgs[(wn + j * 16 + l15) * LDSP + quad * 8];
            bu[j] = *(const bf16x8*)&Bus[(wn + j * 16 + l15) * LDSP + quad * 8];
        }
        #pragma unroll
        for (int i = 0; i < 4; i++)
            #pragma unroll
            for (int j = 0; j < 4; j++) {
                accg[i][j] = __builtin_amdgcn_mfma_f32_16x16x32_bf16(af[i], bg[j], accg[i][j], 0, 0, 0);
                accu[i][j] = __builtin_amdgcn_mfma_f32_16x16x32_bf16(af[i], bu[j], accu[i][j], 0, 0, 0);
            }
    }

    #pragma unroll
    for (int i = 0; i < 4; i++) {
        #pragma unroll
        for (int r = 0; r < 4; r++) {
            int t = t0 + wm + i * 16 + quad * 4 + r;
            float sc = comb ? comb[(size_t)t * E_NUM + z] : 1.f;
            #pragma unroll
            for (int j = 0; j < 4; j++) {
                float g = accg[i][j][r], u = accu[i][j][r];
                float sg = g / (1.f + __expf(-g));
                float v = sg * u * sc;
                int c = n0 + wn + j * 16 + l15;
                C[(size_t)t * ldc + c] = f2bf(v);
            }
        }
    }
}

__global__ __launch_bounds__(256)
void gemm2_kernel(const ushort_t* __restrict__ A0, size_t aSeg, int lda,
                  const float* __restrict__ B0, size_t bSeg, int ldb,
                  float* __restrict__ Out, int N,
                  int nseg, int Kper, int accum)
{
    __shared__ ushort_t Als[BM * LDSP];
    __shared__ ushort_t Bls[BN * LDSP];

    int t0 = blockIdx.x * BM;
    int n0 = blockIdx.y * BN;
    int tid = threadIdx.x;
    int lane = tid & 63, wid = tid >> 6;
    int wm = (wid & 1) * 64, wn = (wid >> 1) * 64;
    int quad = lane >> 4, l15 = lane & 15;

    float4v acc[4][4];
    #pragma unroll
    for (int i = 0; i < 4; i++)
        #pragma unroll
        for (int j = 0; j < 4; j++) acc[i][j] = (float4v){0.f, 0.f, 0.f, 0.f};

    int a_r  = tid >> 2, a_oc = tid & 3;
    int b_ko = (tid >> 4) & 3;
    int b_n  = 2 * ((tid & 15) + ((tid >> 6) << 4));

    for (int seg = 0; seg < nseg; seg++) {
        const ushort_t* A = A0 + (size_t)seg * aSeg;
        const float*    B = B0 + (size_t)seg * bSeg;
        for (int k0 = 0; k0 < Kper; k0 += BK) {
            __syncthreads();
            {
                const ushort_t* s0 = A + (size_t)(t0 + a_r) * lda + k0 + a_oc * 8;
                *(short8*)&Als[a_r * LDSP + a_oc * 8] = *(const short8*)s0;
                const ushort_t* s1 = A + (size_t)(t0 + a_r + 64) * lda + k0 + a_oc * 8;
                *(short8*)&Als[(a_r + 64) * LDSP + a_oc * 8] = *(const short8*)s1;
            }
            {
                short8 r0, r1;
                #pragma unroll
                for (int j = 0; j < 8; j++) {
                    size_t roff = (size_t)(k0 + b_ko * 8 + j) * ldb + n0 + b_n;
                    float2 v = *(const float2*)&B[roff];
                    r0[j] = (short)f2bf(v.x); r1[j] = (short)f2bf(v.y);
                }
                *(short8*)&Bls[b_n * LDSP + b_ko * 8]       = r0;
                *(short8*)&Bls[(b_n + 1) * LDSP + b_ko * 8] = r1;
            }
            __syncthreads();

            bf16x8 af[4], bf[4];
            #pragma unroll
            for (int i = 0; i < 4; i++)
                af[i] = *(const bf16x8*)&Als[(wm + i * 16 + l15) * LDSP + quad * 8];
            #pragma unroll
            for (int j = 0; j < 4; j++)
                bf[j] = *(const bf16x8*)&Bls[(wn + j * 16 + l15) * LDSP + quad * 8];
            #pragma unroll
            for (int i = 0; i < 4; i++)
                #pragma unroll
                for (int j = 0; j < 4; j++)
                    acc[i][j] = __builtin_amdgcn_mfma_f32_16x16x32_bf16(af[i], bf[j], acc[i][j], 0, 0, 0);
        }
    }

    #pragma unroll
    for (int i = 0; i < 4; i++) {
        #pragma unroll
        for (int r = 0; r < 4; r++) {
            int t = t0 + wm + i * 16 + quad * 4 + r;
            #pragma unroll
            for (int j = 0; j < 4; j++) {
                int c = n0 + wn + j * 16 + l15;
                size_t idx = (size_t)t * N + c;
                float v = acc[i][j][r];
                if (accum) Out[idx] += v; else Out[idx] = v;
            }
        }
    }
}

// =====================================================================================

extern "C" void kernel_launch(void* const* d_in, const int* in_sizes, int n_in,
                              void* d_out, int out_size, void* d_ws, size_t ws_size,
                              hipStream_t stream) {
    const float* h      = (const float*)d_in[0];
    const float* gate_w = (const float*)d_in[1];
    const float* Wg     = (const float*)d_in[2];
    const float* Wu     = (const float*)d_in[3];
    const float* Wd     = (const float*)d_in[4];
    const float* sWg    = (const float*)d_in[5];
    const float* sWu    = (const float*)d_in[6];
    const float* sWd    = (const float*)d_in[7];
    float* out = (float*)d_out;
    int T = in_sizes[0] / H_DIM;
    (void)n_in; (void)out_size;

    char* ws = (char*)d_ws;
    size_t off = 0;
    auto alloc = [&](size_t bytes) -> void* {
        void* p = ws + off;
        off = (off + bytes + 255) & ~(size_t)255;
        return p;
    };
    ushort_t* h_bf  = (ushort_t*)alloc((size_t)T * H_DIM * 2);
    float*    comb  = (float*)   alloc((size_t)T * E_NUM * 4);
    ushort_t* act_s = (ushort_t*)alloc((size_t)T * IS_DIM * 2);
    ushort_t* act_r = (ushort_t*)alloc((size_t)E_NUM * T * IM_DIM * 2);
    ushort_t* bufS1 = (ushort_t*)alloc((size_t)IS_DIM * H_DIM * 2);          // 8 MB
    ushort_t* bufS2 = (ushort_t*)alloc((size_t)IS_DIM * H_DIM * 2);          // 8 MB
    ushort_t* bufW1 = (ushort_t*)alloc((size_t)E_NUM * IM_DIM * H_DIM * 2);  // 64 MB
    ushort_t* bufW2 = (ushort_t*)alloc((size_t)E_NUM * IM_DIM * H_DIM * 2);  // 64 MB
    size_t need = off;

    int n4 = T * H_DIM / 4;

    if (ws_size >= need) {
        // ---- fast path: 6 launches ----
        cast_zero_kernel<<<(n4 + 255) / 256, 256, 0, stream>>>(h, h_bf, (float4*)out, n4);
        router_kernel<<<T, 64, 0, stream>>>(h, gate_w, comb, T);

        // all gate/up transposes (routed + shared slices) in one launch
        transpose_gu_kernel<<<dim3(H_DIM / 64, IM_DIM / 256, E_NUM + 2), 512, 0, stream>>>(
            Wg, Wu, sWg, sWu, bufW1, bufW2, bufS1, bufS2);

        // all of gemm1 (routed + shared) in one launch
        gemm1u_kernel<<<dim3(T / BM, IM_DIM / BN, E_NUM + 2), 256, 0, stream>>>(
            h_bf, bufW1, bufW2, bufS1, bufS2, act_r, act_s, comb, T);

        // all down transposes in one launch (reuse bufW2/bufS2, dead after gemm1)
        transpose_d_kernel<<<dim3(IM_DIM / 64, H_DIM / 256, E_NUM + 2), 512, 0, stream>>>(
            Wd, sWd, bufW2, bufS2);

        // all of gemm2 (18 segments over 2 z-groups) in one launch, atomic onto zeroed out
        gemm2u_kernel<<<dim3(T / BM, H_DIM / BN, 2), 256, 0, stream>>>(
            act_r, act_s, bufW2, bufS2, out, T, (E_NUM + 2) / 2);
    } else {
        // ---- fallback: round-1 path (~80 MB ws) ----
        cast_zero_kernel<<<(n4 + 255) / 256, 256, 0, stream>>>(h, h_bf, (float4*)out, n4);
        router_kernel<<<T, 64, 0, stream>>>(h, gate_w, comb, T);
        gemm1_kernel<<<dim3(T / BM, IS_DIM / BN, 1), 256, 0, stream>>>(
            h_bf, H_DIM, sWg, sWu, 0, IS_DIM, act_s, 0, IS_DIM, nullptr, H_DIM);
        gemm1_kernel<<<dim3(T / BM, IM_DIM / BN, E_NUM), 256, 0, stream>>>(
            h_bf, H_DIM, Wg, Wu, (size_t)H_DIM * IM_DIM, IM_DIM,
            act_r, (size_t)T * IM_DIM, IM_DIM, comb, H_DIM);
        gemm2_kernel<<<dim3(T / BM, H_DIM / BN, 1), 256, 0, stream>>>(
            act_s, 0, IS_DIM, sWd, 0, H_DIM, out, H_DIM, 1, IS_DIM, 1);
        gemm2_kernel<<<dim3(T / BM, H_DIM / BN, 1), 256, 0, stream>>>(
            act_r, (size_t)T * IM_DIM, IM_DIM, Wd, (size_t)IM_DIM * H_DIM, H_DIM,
            out, H_DIM, E_NUM, IM_DIM, 1);
    }
}